// Round 2
// baseline (2057.203 us; speedup 1.0000x reference)
//
#include <hip/hip_runtime.h>
#include <hip/hip_bf16.h>

#define B_ 32
#define L_ 4096
#define DIN 16
#define H_ 128
#define N2_ 32
#define NL_ 4
#define DOUT_ 8
#define CL 64   // chunk length
#define NC 64   // chunks per sequence (L/CL)

// ---- workspace layout (in floats) ----
#define OFF_U   ((size_t)0)
#define SZ_U    ((size_t)B_*H_*L_)            // activations, [b][h][l]
#define OFF_Y   (OFF_U + SZ_U)
#define SZ_Y    SZ_U                          // post-GELU SSM output
#define OFF_T1  (OFF_Y + SZ_Y)
#define SZ_T1   ((size_t)NL_*H_*64*64)        // [l][h][e][np]  w^e, e=0..63 (np = 2n+part)
#define OFF_T2  (OFF_T1 + SZ_T1)
#define SZ_T2   ((size_t)NL_*H_*64*68)        // [l][h][np][tau] w^{tau+1}, row pad 68
#define OFF_K   (OFF_T2 + SZ_T2)
#define SZ_K    ((size_t)NL_*H_*64)           // k[h][s], s<64
#define OFF_CP  (OFF_K + SZ_K)
#define SZ_CP   ((size_t)NL_*H_*64)           // C' [l][h][n][2]
#define OFF_W64 (OFF_CP + SZ_CP)
#define SZ_W64  ((size_t)NL_*H_*64)           // w^64 [l][h][n][2]
#define OFF_PL  (OFF_W64 + SZ_W64)
#define SZ_PL   ((size_t)B_*H_)

// ---------------------------------------------------------------------------
// P0a: per (layer,h,n) compute w=exp(dtA), C'=(C)*(w-1)/A, power tables
// ---------------------------------------------------------------------------
__global__ __launch_bounds__(256) void prep_tables(const float* log_dt, const float* log_A_real,
                                                   const float* A_imag, const float* C_re,
                                                   const float* C_im, float* ws) {
    int idx = blockIdx.x * 256 + threadIdx.x;        // flat (l,h,n)
    if (idx >= NL_ * H_ * N2_) return;
    int n  = idx & 31;
    int lh = idx >> 5;                               // l*128 + h

    float dt  = expf(log_dt[lh]);
    float Are = -expf(log_A_real[idx]);
    float Aim = A_imag[idx];
    float dre = Are * dt, dim = Aim * dt;
    float er  = expf(dre);
    float wre = er * cosf(dim), wim = er * sinf(dim);
    // (w-1)/A
    float nre = wre - 1.0f, nim = wim;
    float den = Are * Are + Aim * Aim;
    float qre = (nre * Are + nim * Aim) / den;
    float qim = (nim * Are - nre * Aim) / den;
    float cre = C_re[idx], cim = C_im[idx];
    float Cpre = cre * qre - cim * qim;
    float Cpim = cre * qim + cim * qre;

    float* t1  = ws + OFF_T1  + (size_t)lh * 64 * 64;
    float* t2  = ws + OFF_T2  + (size_t)lh * 64 * 68;
    float* cp  = ws + OFF_CP  + (size_t)lh * 64;
    float* w64 = ws + OFF_W64 + (size_t)lh * 64;
    cp[2 * n] = Cpre; cp[2 * n + 1] = Cpim;

    float pr = 1.0f, pi = 0.0f;                      // w^0
    for (int e = 0; e < 64; ++e) {
        t1[e * 64 + 2 * n]     = pr;                 // w^e
        t1[e * 64 + 2 * n + 1] = pi;
        float npr = pr * wre - pi * wim;
        float npi = pr * wim + pi * wre;
        pr = npr; pi = npi;                          // now w^{e+1}
        t2[(2 * n) * 68 + e]     = pr;               // w^{tau+1} at tau=e
        t2[(2 * n + 1) * 68 + e] = pi;
    }
    w64[2 * n] = pr; w64[2 * n + 1] = pi;            // w^64
}

// ---------------------------------------------------------------------------
// P0b: k[h][s] = 2*Re( sum_n C'_n w_n^s ),  s = 0..63 (local conv taps)
// ---------------------------------------------------------------------------
__global__ __launch_bounds__(256) void compute_k(float* ws) {
    int idx = blockIdx.x * 256 + threadIdx.x;        // (l,h,s)
    if (idx >= NL_ * H_ * 64) return;
    int s  = idx & 63;
    int lh = idx >> 6;
    const float* t1 = ws + OFF_T1 + (size_t)lh * 64 * 64 + (size_t)s * 64;
    const float* cp = ws + OFF_CP + (size_t)lh * 64;
    float acc = 0.0f;
    #pragma unroll
    for (int n = 0; n < 32; ++n)
        acc += cp[2 * n] * t1[2 * n] - cp[2 * n + 1] * t1[2 * n + 1];
    ws[OFF_K + (size_t)lh * 64 + s] = 2.0f * acc;
}

// ---------------------------------------------------------------------------
// Encoder: u[b][h][l] = enc_b[h] + sum_d x[b][l][d]*enc_w[h][d]
// ---------------------------------------------------------------------------
__global__ __launch_bounds__(256) void encoder_kernel(const float* x, const float* enc_w,
                                                      const float* enc_b, float* ws) {
    __shared__ float wlds[H_ * DIN];
    __shared__ float blds[H_];
    int t  = threadIdx.x;
    int b  = blockIdx.x >> 4;                        // 16 l-tiles of 256
    int l0 = (blockIdx.x & 15) * 256;
    for (int i = t; i < H_ * DIN; i += 256) wlds[i] = enc_w[i];
    if (t < H_) blds[t] = enc_b[t];
    float xr[16];
    const float* xp = x + ((size_t)b * L_ + l0 + t) * DIN;
    #pragma unroll
    for (int d = 0; d < 16; ++d) xr[d] = xp[d];
    __syncthreads();
    float* u = ws + OFF_U + (size_t)b * H_ * L_ + l0 + t;
    for (int h = 0; h < H_; ++h) {
        float acc = blds[h];
        #pragma unroll
        for (int d = 0; d < 16; ++d) acc += xr[d] * wlds[h * 16 + d];
        u[(size_t)h * L_] = acc;
    }
}

// ---------------------------------------------------------------------------
// S4D chunked scan, fused P1+P2+P3, one block per (b,h).
//   y[t] = GELU( conv(k, z)[t] + D*z[t] )
//   conv decomposed: local Toeplitz within 64-chunk + state term via w^{tau+1}
// ---------------------------------------------------------------------------
__global__ __launch_bounds__(256) void s4d_scan(const float* Dp, float* ws, int layer) {
    __shared__ float z_lds[L_];          // 16 KB
    __shared__ float eg_lds[NC * 64];    // 16 KB: E then g' in-place
    __shared__ float k_ext[128];         // zero-padded taps

    int t    = threadIdx.x;
    int b    = blockIdx.x >> 7;
    int h    = blockIdx.x & 127;
    int lh   = layer * H_ + h;
    int wv   = t >> 6;                   // wave 0..3
    int lane = t & 63;

    const float* u = ws + OFF_U + ((size_t)b * H_ + h) * L_;
    for (int i = t; i < L_ / 4; i += 256)
        ((float4*)z_lds)[i] = ((const float4*)u)[i];
    if (t < 64) k_ext[t] = 0.0f;
    else if (t < 128) k_ext[t] = ws[OFF_K + (size_t)lh * 64 + (t - 64)];

    // t1 column (w^e parts for this lane's np) -> regs
    float t1r[64];
    {
        const float* t1 = ws + OFF_T1 + (size_t)lh * 4096 + lane;
        #pragma unroll
        for (int e = 0; e < 64; ++e) t1r[e] = t1[e * 64];
    }
    __syncthreads();

    // ---- P1: chunk-local end states E_c[np] = sum_s w^{63-s} z[c*64+s]
    for (int j = 0; j < 16; ++j) {
        int c = wv * 16 + j;
        float acc = 0.0f;
        #pragma unroll
        for (int e4 = 0; e4 < 16; ++e4) {
            float4 zv = *(const float4*)&z_lds[c * 64 + 60 - 4 * e4];
            acc += t1r[4 * e4 + 0] * zv.w;   // z[63-e]
            acc += t1r[4 * e4 + 1] * zv.z;
            acc += t1r[4 * e4 + 2] * zv.y;
            acc += t1r[4 * e4 + 3] * zv.x;
        }
        eg_lds[c * 64 + lane] = acc;
    }
    __syncthreads();

    // ---- P2: scan S_{c+1} = w^64 * S_c + E_c; write g' = 2*C'*S_c (sign-folded)
    if (t < 32) {
        int n = t;
        const float* cp  = ws + OFF_CP  + (size_t)lh * 64;
        const float* w64 = ws + OFF_W64 + (size_t)lh * 64;
        float cre = cp[2 * n], cim = cp[2 * n + 1];
        float wr  = w64[2 * n], wi = w64[2 * n + 1];
        float sre = 0.0f, sim = 0.0f;
        for (int c = 0; c < NC; ++c) {
            float ere = eg_lds[c * 64 + 2 * n];
            float eim = eg_lds[c * 64 + 2 * n + 1];
            eg_lds[c * 64 + 2 * n]     = 2.0f * (cre * sre - cim * sim);
            eg_lds[c * 64 + 2 * n + 1] = -2.0f * (cre * sim + cim * sre);
            float nsre = wr * sre - wi * sim + ere;
            float nsim = wr * sim + wi * sre + eim;
            sre = nsre; sim = nsim;
        }
    }
    // t2 column (w^{tau+1} parts, this lane's tau) -> regs
    float t2r[64];
    {
        const float* t2 = ws + OFF_T2 + (size_t)lh * 64 * 68 + lane;
        #pragma unroll
        for (int np = 0; np < 64; ++np) t2r[np] = t2[np * 68];
    }
    float Dh = Dp[lh];
    __syncthreads();

    // ---- P3: outputs
    float* y = ws + OFF_Y + ((size_t)b * H_ + h) * L_;
    for (int j = 0; j < 16; ++j) {
        int c   = wv * 16 + j;
        int tau = lane;
        float zt  = z_lds[c * 64 + tau];
        float acc = Dh * zt;
        // state term: sum_np g'[np] * w^{tau+1}[np]
        #pragma unroll
        for (int m = 0; m < 16; ++m) {
            float4 gv = *(const float4*)&eg_lds[c * 64 + 4 * m];
            acc += gv.x * t2r[4 * m + 0];
            acc += gv.y * t2r[4 * m + 1];
            acc += gv.z * t2r[4 * m + 2];
            acc += gv.w * t2r[4 * m + 3];
        }
        // local conv: sum_sigma z[sigma] * k_ext[64 + tau - sigma]
        #pragma unroll
        for (int s4 = 0; s4 < 16; ++s4) {
            float4 zv = *(const float4*)&z_lds[c * 64 + 4 * s4];
            acc += zv.x * k_ext[64 + tau - 4 * s4 - 0];
            acc += zv.y * k_ext[64 + tau - 4 * s4 - 1];
            acc += zv.z * k_ext[64 + tau - 4 * s4 - 2];
            acc += zv.w * k_ext[64 + tau - 4 * s4 - 3];
        }
        float g = 0.5f * acc * (1.0f + erff(acc * 0.70710678118654752f));
        y[c * 64 + tau] = g;
    }
}

// ---------------------------------------------------------------------------
// Channel mix: v = conv_w @ y + conv_b ; GLU ; +residual u ; LayerNorm -> u
// One block = (b, 64 l-positions). fp32 register-tiled GEMM 256x64, K=128.
// ---------------------------------------------------------------------------
__global__ __launch_bounds__(256) void conv_glu_ln(const float* conv_w, const float* conv_b,
                                                   const float* ln_w, const float* ln_b,
                                                   float* ws, int layer) {
    __shared__ float Wlds[16 * 260];     // [k][o], pad 260
    __shared__ float Ylds[16 * 68];      // [k][l], pad 68

    int t    = threadIdx.x;
    int b    = blockIdx.x >> 6;
    int l0   = (blockIdx.x & 63) * 64;
    int ocol = t & 31;
    int lgrp = t >> 5;

    const float* Wg = conv_w + (size_t)layer * 256 * 128;
    const float* yg = ws + OFF_Y + (size_t)b * H_ * L_;

    float acc[8][8];
    #pragma unroll
    for (int j = 0; j < 8; ++j) {
        int o = (j < 4) ? (4 * ocol + j) : (124 + 4 * ocol + j);
        float cb = conv_b[layer * 256 + o];
        #pragma unroll
        for (int i = 0; i < 8; ++i) acc[j][i] = cb;
    }

    for (int k0 = 0; k0 < 128; k0 += 16) {
        __syncthreads();
        {   // stage W tile: [o=t][k0..k0+15]
            const float* wrow = Wg + (size_t)t * 128 + k0;
            float4 a = *(const float4*)(wrow);
            float4 bb = *(const float4*)(wrow + 4);
            float4 cc = *(const float4*)(wrow + 8);
            float4 dd = *(const float4*)(wrow + 12);
            float wv16[16] = {a.x,a.y,a.z,a.w, bb.x,bb.y,bb.z,bb.w,
                              cc.x,cc.y,cc.z,cc.w, dd.x,dd.y,dd.z,dd.w};
            #pragma unroll
            for (int kk = 0; kk < 16; ++kk) Wlds[kk * 260 + t] = wv16[kk];
        }
        {   // stage Y tile
            int kk = t >> 4, l4 = (t & 15) * 4;
            float4 v = *(const float4*)&yg[(size_t)(k0 + kk) * L_ + l0 + l4];
            *(float4*)&Ylds[kk * 68 + l4] = v;
        }
        __syncthreads();
        #pragma unroll
        for (int kk = 0; kk < 16; ++kk) {
            float4 w0 = *(const float4*)&Wlds[kk * 260 + 4 * ocol];
            float4 w1 = *(const float4*)&Wlds[kk * 260 + 4 * ocol + 128];
            float4 y0 = *(const float4*)&Ylds[kk * 68 + lgrp * 8];
            float4 y1 = *(const float4*)&Ylds[kk * 68 + lgrp * 8 + 4];
            float wj[8] = {w0.x, w0.y, w0.z, w0.w, w1.x, w1.y, w1.z, w1.w};
            float yi[8] = {y0.x, y0.y, y0.z, y0.w, y1.x, y1.y, y1.z, y1.w};
            #pragma unroll
            for (int j = 0; j < 8; ++j)
                #pragma unroll
                for (int i = 0; i < 8; ++i)
                    acc[j][i] += wj[j] * yi[i];
        }
    }

    // GLU + residual
    float* ug = ws + OFF_U + (size_t)b * H_ * L_;
    float r[4][8];
    #pragma unroll
    for (int j = 0; j < 4; ++j) {
        int hch = 4 * ocol + j;
        const float* up = ug + (size_t)hch * L_ + l0 + lgrp * 8;
        float4 u0 = *(const float4*)up;
        float4 u1 = *(const float4*)(up + 4);
        float ui[8] = {u0.x, u0.y, u0.z, u0.w, u1.x, u1.y, u1.z, u1.w};
        #pragma unroll
        for (int i = 0; i < 8; ++i) {
            float a = acc[j][i], g = acc[j + 4][i];
            float y2 = a / (1.0f + expf(-g));
            r[j][i] = y2 + ui[i];
        }
    }
    // LayerNorm stats across 128 channels (32 lanes x 4 ch each)
    float mu[8], s2[8];
    #pragma unroll
    for (int i = 0; i < 8; ++i) {
        float s = r[0][i] + r[1][i] + r[2][i] + r[3][i];
        float q = r[0][i] * r[0][i] + r[1][i] * r[1][i] + r[2][i] * r[2][i] + r[3][i] * r[3][i];
        #pragma unroll
        for (int m = 1; m <= 16; m <<= 1) {
            s += __shfl_xor(s, m, 64);
            q += __shfl_xor(q, m, 64);
        }
        mu[i] = s * (1.0f / 128.0f);
        s2[i] = q * (1.0f / 128.0f) - mu[i] * mu[i];
    }
    #pragma unroll
    for (int j = 0; j < 4; ++j) {
        int hch = 4 * ocol + j;
        float lw = ln_w[layer * 128 + hch], lb = ln_b[layer * 128 + hch];
        float o0[4], o1[4];
        #pragma unroll
        for (int i = 0; i < 8; ++i) {
            float rstd = rsqrtf(s2[i] + 1e-5f);
            float v = (r[j][i] - mu[i]) * rstd * lw + lb;
            if (i < 4) o0[i] = v; else o1[i - 4] = v;
        }
        float* up = ug + (size_t)hch * L_ + l0 + lgrp * 8;
        *(float4*)up       = make_float4(o0[0], o0[1], o0[2], o0[3]);
        *(float4*)(up + 4) = make_float4(o1[0], o1[1], o1[2], o1[3]);
    }
}

// ---------------------------------------------------------------------------
// Mean-pool over L per (b,h)
// ---------------------------------------------------------------------------
__global__ __launch_bounds__(256) void pool_kernel(float* ws) {
    int bh = blockIdx.x;
    const float* u = ws + OFF_U + (size_t)bh * L_;
    int t = threadIdx.x;
    float s = 0.0f;
    for (int i = t; i < L_; i += 256) s += u[i];
    #pragma unroll
    for (int m = 1; m <= 32; m <<= 1) s += __shfl_xor(s, m, 64);
    __shared__ float part[4];
    if ((t & 63) == 0) part[t >> 6] = s;
    __syncthreads();
    if (t == 0) ws[OFF_PL + bh] = (part[0] + part[1] + part[2] + part[3]) * (1.0f / L_);
}

// ---------------------------------------------------------------------------
// Decoder: pred[b][o] = sigmoid(pooled[b] . dec_w[o] + dec_b[o])  (f32 out)
// ---------------------------------------------------------------------------
__global__ __launch_bounds__(256) void decode_kernel(const float* dec_w, const float* dec_b,
                                                     const float* ws, float* out) {
    int t = threadIdx.x;
    int b = t >> 3, o = t & 7;
    const float* p = ws + OFF_PL + b * 128;
    float acc = dec_b[o];
    for (int h = 0; h < 128; ++h) acc += p[h] * dec_w[o * 128 + h];
    out[t] = 1.0f / (1.0f + expf(-acc));
}

// ---------------------------------------------------------------------------
// emb output: out[b][l][h] = u[b][h][l]  (f32, LDS tile transpose)
// ---------------------------------------------------------------------------
__global__ __launch_bounds__(256) void emb_out(const float* uws, float* out) {
    __shared__ float T[32 * 65];
    int t  = threadIdx.x;
    int bi = blockIdx.x;
    int lt = bi & 63;
    int ht = (bi >> 6) & 3;
    int b  = bi >> 8;
    int l0 = lt * 64, h0 = ht * 32;
    const float* u = uws + ((size_t)b * H_ + h0) * L_ + l0;
    #pragma unroll
    for (int p = 0; p < 8; ++p) {
        int rr = p * 4 + (t >> 6), cc = t & 63;
        T[rr * 65 + cc] = u[(size_t)rr * L_ + cc];
    }
    __syncthreads();
    #pragma unroll
    for (int q = 0; q < 8; ++q) {
        int hh = t & 31, ll = (t >> 5) + q * 8;
        out[((size_t)(b * L_) + l0 + ll) * H_ + h0 + hh] = T[hh * 65 + ll];
    }
}

// ---------------------------------------------------------------------------
extern "C" void kernel_launch(void* const* d_in, const int* in_sizes, int n_in,
                              void* d_out, int out_size, void* d_ws, size_t ws_size,
                              hipStream_t stream) {
    const float* x          = (const float*)d_in[0];
    // d_in[1] = times (unused by reference)
    const float* enc_w      = (const float*)d_in[2];
    const float* enc_b      = (const float*)d_in[3];
    const float* log_dt     = (const float*)d_in[4];
    const float* log_A_real = (const float*)d_in[5];
    const float* A_imag     = (const float*)d_in[6];
    const float* C_re       = (const float*)d_in[7];
    const float* C_im       = (const float*)d_in[8];
    const float* Dp         = (const float*)d_in[9];
    const float* conv_w     = (const float*)d_in[10];
    const float* conv_b     = (const float*)d_in[11];
    const float* ln_w       = (const float*)d_in[12];
    const float* ln_b       = (const float*)d_in[13];
    const float* dec_w      = (const float*)d_in[14];
    const float* dec_b      = (const float*)d_in[15];
    float* ws = (float*)d_ws;
    float* out = (float*)d_out;

    prep_tables<<<(NL_ * H_ * N2_ + 255) / 256, 256, 0, stream>>>(log_dt, log_A_real, A_imag,
                                                                  C_re, C_im, ws);
    compute_k<<<(NL_ * H_ * 64 + 255) / 256, 256, 0, stream>>>(ws);
    encoder_kernel<<<B_ * (L_ / 256), 256, 0, stream>>>(x, enc_w, enc_b, ws);
    for (int l = 0; l < NL_; ++l) {
        s4d_scan<<<B_ * H_, 256, 0, stream>>>(Dp, ws, l);
        conv_glu_ln<<<B_ * (L_ / 64), 256, 0, stream>>>(conv_w, conv_b, ln_w, ln_b, ws, l);
    }
    pool_kernel<<<B_ * H_, 256, 0, stream>>>(ws);
    decode_kernel<<<1, 256, 0, stream>>>(dec_w, dec_b, ws, out);
    emb_out<<<B_ * 4 * 64, 256, 0, stream>>>(ws + OFF_U, out + 256);
}